// Round 1
// baseline (458.885 us; speedup 1.0000x reference)
//
#include <hip/hip_runtime.h>
#include <cstdint>

typedef float f32x4 __attribute__((ext_vector_type(4)));
typedef short bf16x8 __attribute__((ext_vector_type(8)));

#define QP_BASE 0
#define KP_BASE 16384
#define VT_BASE 32768
#define P_BASE  49152

__device__ __forceinline__ unsigned short f2bf(float f){
  union { float f; uint32_t u; } v; v.f = f;
  uint32_t u = v.u;
  return (unsigned short)((u + 0x7FFFu + ((u >> 16) & 1u)) >> 16);  // RNE
}
__device__ __forceinline__ float bf2f(unsigned short h){
  union { uint32_t u; float f; } v; v.u = ((uint32_t)h) << 16;
  return v.f;
}
__device__ __forceinline__ f32x4 mfma16x16x32(bf16x8 a, bf16x8 b, f32x4 c){
  return __builtin_amdgcn_mfma_f32_16x16x32_bf16(a, b, c, 0, 0, 0);
}

// ---------------- prep: transpose weights to bf16 [N][K], split w_o hi/lo, expand bias ----
// ws layout (bytes): WT_q 0..32K, WT_v 32K..64K, WT_k 64K..128K, WT_o_hi 128K..160K,
//                    WT_o_lo 160K..192K, bias_exp f32 192K..320K
__global__ void prep_kernel(const float* __restrict__ wq, const float* __restrict__ wk,
                            const float* __restrict__ wv, const float* __restrict__ wo,
                            const float* __restrict__ btab, unsigned short* __restrict__ wsu)
{
  const int idx = blockIdx.x * 256 + threadIdx.x;
  if (idx < 16384){                          // WT_q[n][k] = wq[k][n]
    const int n = idx >> 7, k = idx & 127;
    wsu[n*128 + k] = f2bf(wq[k*128 + n]);
  } else if (idx < 32768){                   // WT_v
    const int i = idx - 16384, n = i >> 7, k = i & 127;
    wsu[16384 + n*128 + k] = f2bf(wv[k*128 + n]);
  } else if (idx < 65536){                   // WT_k (K=256)
    const int i = idx - 32768, n = i >> 8, k = i & 255;
    wsu[32768 + n*256 + k] = f2bf(wk[k*128 + n]);
  } else if (idx < 81920){                   // WT_o hi/lo
    const int i = idx - 65536, n = i >> 7, k = i & 127;
    const float f = wo[k*128 + n];
    const unsigned short hv = f2bf(f);
    wsu[65536 + n*128 + k] = hv;
    wsu[81920 + n*128 + k] = f2bf(f - bf2f(hv));
  } else if (idx < 114688){                  // bias_exp[h][q][k]
    const int i = idx - 81920;
    const int h = i >> 12, q = (i >> 6) & 63, kx = i & 63;
    const int qi = q >> 3, qj = q & 7, ki = kx >> 3, kj = kx & 7;
    const int rel = (qi - ki + 7) * 15 + (qj - kj + 7);
    reinterpret_cast<float*>(wsu + 98304)[i] = btab[rel*8 + h];
  }
}

// ---------------- fused per-window kernel ----------------
// DEST: 0 -> qp_lds [64row][128ch] bf16 swz, 1 -> kp_lds same, 2 -> vp_t [8h][16ch][64key] bf16 swz
template<int KC, int DEST>
__device__ __forceinline__ void proj_phase(const float* __restrict__ X,
    const unsigned short* __restrict__ WT, const float* __restrict__ bias,
    char* smem, long winbase, int wave, int lane)
{
  const int g = lane >> 4, c16 = lane & 15;
  constexpr int NKS = KC / 32;
  const int rA = 16*wave + c16;                       // A-fragment row (window-local)
  const long tokA = winbase + (long)(rA >> 3) * 256 + (rA & 7);
  const float* xrow = X + tokA * KC;
  bf16x8 a[NKS];
#pragma unroll
  for (int ks = 0; ks < NKS; ++ks){
    const float4* p = reinterpret_cast<const float4*>(xrow + 32*ks + 8*g);
    const float4 x0 = p[0], x1 = p[1];
    bf16x8 t;
    t[0]=(short)f2bf(x0.x); t[1]=(short)f2bf(x0.y); t[2]=(short)f2bf(x0.z); t[3]=(short)f2bf(x0.w);
    t[4]=(short)f2bf(x1.x); t[5]=(short)f2bf(x1.y); t[6]=(short)f2bf(x1.z); t[7]=(short)f2bf(x1.w);
    a[ks] = t;
  }
  f32x4 acc[8];
#pragma unroll
  for (int ct = 0; ct < 8; ++ct) acc[ct] = f32x4{0.f,0.f,0.f,0.f};
#pragma unroll
  for (int ct = 0; ct < 8; ++ct){
    const unsigned short* wrow = WT + (ct*16 + c16) * KC + 8*g;   // B-frag: [N][K] contiguous
#pragma unroll
    for (int ks = 0; ks < NKS; ++ks){
      const bf16x8 b = *reinterpret_cast<const bf16x8*>(wrow + 32*ks);
      acc[ct] = mfma16x16x32(a[ks], b, acc[ct]);
    }
  }
#pragma unroll
  for (int ct = 0; ct < 8; ++ct){
    const float bsv = bias[ct*16 + c16];
#pragma unroll
    for (int r = 0; r < 4; ++r){
      const float v = acc[ct][r] + bsv;
      const unsigned short hv = f2bf(v);
      const int row = 16*wave + 4*g + r;              // C-layout row
      int off;
      if (DEST == 0)
        off = QP_BASE + (((row << 8) + ((ct*16 + c16) << 1)) ^ ((row & 7) << 4));
      else if (DEST == 1)
        off = KP_BASE + (((row << 8) + ((ct*16 + c16) << 1)) ^ ((row & 7) << 4));
      else  // vp transposed: head = ct, ch-in-head = c16, key = row
        off = VT_BASE + (((ct << 11) + (c16 << 7) + (row << 1)) ^ ((c16 & 7) << 4));
      *reinterpret_cast<unsigned short*>(smem + off) = hv;
    }
  }
}

__global__ __launch_bounds__(256, 2) void fused_win_attn(
    const float* __restrict__ qq, const float* __restrict__ kkin, const float* __restrict__ vvin,
    const float* __restrict__ b_q, const float* __restrict__ b_k, const float* __restrict__ b_v,
    const float* __restrict__ b_o, const unsigned short* __restrict__ wsu,
    float* __restrict__ out)
{
  __shared__ char smem[57344];   // qp 16K | kp 16K | vp_t 16K | P 8K ; y reuses [0,32K) later
  const int tid = threadIdx.x;
  const int wave = tid >> 6, lane = tid & 63;
  const int g = lane >> 4, c16 = lane & 15;
  const int wi = blockIdx.x;
  const int bb = wi >> 10, wy = (wi >> 5) & 31, wx = wi & 31;
  const long winbase = (long)bb * 65536 + (long)wy * 2048 + wx * 8;

  const unsigned short* WT_q  = wsu;
  const unsigned short* WT_v  = wsu + 16384;
  const unsigned short* WT_k  = wsu + 32768;
  const unsigned short* WT_oh = wsu + 65536;
  const unsigned short* WT_ol = wsu + 81920;
  const float* bias_exp = reinterpret_cast<const float*>(wsu + 98304);

  // ---- Phase A: q/k/v projections into LDS ----
  proj_phase<128,0>(qq,   WT_q, b_q, smem, winbase, wave, lane);
  proj_phase<256,1>(kkin, WT_k, b_k, smem, winbase, wave, lane);
  proj_phase<128,2>(vvin, WT_v, b_v, smem, winbase, wave, lane);
  __syncthreads();

  // ---- Phase B: per-head scores -> softmax -> PV, y kept in registers ----
  float yreg[32];   // [head][reg] — statically indexed (loop fully unrolled)
  const int pbase = P_BASE + wave * 2048;
#pragma unroll
  for (int h = 0; h < 8; ++h){
    // scores: K=16 padded to 32 (lane groups 2,3 supply zeros on both operands)
    bf16x8 aq = {0,0,0,0,0,0,0,0};
    if (g < 2){
      const int row = 16*wave + c16;
      aq = *reinterpret_cast<const bf16x8*>(smem + QP_BASE +
            (((row << 8) + ((h*16 + 8*g) << 1)) ^ ((row & 7) << 4)));
    }
    f32x4 s[4];
#pragma unroll
    for (int kt = 0; kt < 4; ++kt){
      bf16x8 bk8 = {0,0,0,0,0,0,0,0};
      if (g < 2){
        const int row = kt*16 + c16;
        bk8 = *reinterpret_cast<const bf16x8*>(smem + KP_BASE +
              (((row << 8) + ((h*16 + 8*g) << 1)) ^ ((row & 7) << 4)));
      }
      s[kt] = mfma16x16x32(aq, bk8, f32x4{0.f,0.f,0.f,0.f});
    }
    // scale + bias + row softmax (row r lives in the 16 lanes sharing l>>4)
    float p[4][4], rcp[4];
#pragma unroll
    for (int r = 0; r < 4; ++r){
      const int qv = 16*wave + 4*g + r;
      const float* brow = bias_exp + (h*64 + qv)*64 + c16;
      const float s0 = s[0][r]*0.25f + brow[0];
      const float s1 = s[1][r]*0.25f + brow[16];
      const float s2 = s[2][r]*0.25f + brow[32];
      const float s3 = s[3][r]*0.25f + brow[48];
      float m = fmaxf(fmaxf(s0, s1), fmaxf(s2, s3));
      m = fmaxf(m, __shfl_xor(m, 1));
      m = fmaxf(m, __shfl_xor(m, 2));
      m = fmaxf(m, __shfl_xor(m, 4));
      m = fmaxf(m, __shfl_xor(m, 8));
      const float p0 = __expf(s0 - m), p1 = __expf(s1 - m);
      const float p2 = __expf(s2 - m), p3 = __expf(s3 - m);
      float sum = p0 + p1 + p2 + p3;
      sum += __shfl_xor(sum, 1);
      sum += __shfl_xor(sum, 2);
      sum += __shfl_xor(sum, 4);
      sum += __shfl_xor(sum, 8);
      rcp[r] = 1.0f / sum;
      p[0][r]=p0; p[1][r]=p1; p[2][r]=p2; p[3][r]=p3;
    }
    // P -> LDS (per-wave region), C-layout scatter -> A-layout reads
#pragma unroll
    for (int kt = 0; kt < 4; ++kt)
#pragma unroll
      for (int r = 0; r < 4; ++r){
        const int qloc = 4*g + r;
        *reinterpret_cast<unsigned short*>(smem + pbase +
            (((qloc << 7) + ((kt*16 + c16) << 1)) ^ ((qloc & 7) << 4))) = f2bf(p[kt][r]);
      }
    // PV: K=64 keys in 2 MFMAs; V read from transposed [h][ch][key] layout
    f32x4 y = {0.f,0.f,0.f,0.f};
#pragma unroll
    for (int ks = 0; ks < 2; ++ks){
      const bf16x8 ap = *reinterpret_cast<const bf16x8*>(smem + pbase +
          (((c16 << 7) + ((32*ks + 8*g) << 1)) ^ ((c16 & 7) << 4)));
      const bf16x8 bv8 = *reinterpret_cast<const bf16x8*>(smem + VT_BASE +
          (((h << 11) + (c16 << 7) + ((32*ks + 8*g) << 1)) ^ ((c16 & 7) << 4)));
      y = mfma16x16x32(ap, bv8, y);
    }
#pragma unroll
    for (int r = 0; r < 4; ++r) yreg[h*4 + r] = y[r] * rcp[r];
  }

  // ---- Phase C: o-projection (3-term bf16 split for accuracy) ----
  __syncthreads();   // qp/kp now dead for ALL waves; reuse [0,32K) as per-wave fp32 y
  const int ybase = wave * 8192;       // [16 rows][128 ch] fp32, swizzled
#pragma unroll
  for (int h2 = 0; h2 < 8; ++h2)
#pragma unroll
    for (int r = 0; r < 4; ++r){
      const int row = 4*g + r;
      const int ch = h2*16 + c16;
      *reinterpret_cast<float*>(smem + ybase +
          (((row << 9) + (ch << 2)) ^ ((row & 7) << 4))) = yreg[h2*4 + r];
    }
  bf16x8 ahi[4], alo[4];
#pragma unroll
  for (int ks = 0; ks < 4; ++ks){
    const int k0 = 32*ks + 8*g;
    const f32x4 v0 = *reinterpret_cast<const f32x4*>(smem + ybase +
        (((c16 << 9) + (k0 << 2)) ^ ((c16 & 7) << 4)));
    const f32x4 v1 = *reinterpret_cast<const f32x4*>(smem + ybase +
        (((c16 << 9) + ((k0 + 4) << 2)) ^ ((c16 & 7) << 4)));
    bf16x8 h8, l8;
#pragma unroll
    for (int j = 0; j < 4; ++j){
      const unsigned short hh = f2bf(v0[j]);
      h8[j] = (short)hh; l8[j] = (short)f2bf(v0[j] - bf2f(hh));
    }
#pragma unroll
    for (int j = 0; j < 4; ++j){
      const unsigned short hh = f2bf(v1[j]);
      h8[4+j] = (short)hh; l8[4+j] = (short)f2bf(v1[j] - bf2f(hh));
    }
    ahi[ks] = h8; alo[ks] = l8;
  }
#pragma unroll
  for (int ct = 0; ct < 8; ++ct){
    f32x4 acc = {0.f,0.f,0.f,0.f};
    const unsigned short* whrow = WT_oh + (ct*16 + c16)*128 + 8*g;
    const unsigned short* wlrow = WT_ol + (ct*16 + c16)*128 + 8*g;
#pragma unroll
    for (int ks = 0; ks < 4; ++ks){
      const bf16x8 bh = *reinterpret_cast<const bf16x8*>(whrow + 32*ks);
      const bf16x8 bl = *reinterpret_cast<const bf16x8*>(wlrow + 32*ks);
      acc = mfma16x16x32(ahi[ks], bh, acc);
      acc = mfma16x16x32(alo[ks], bh, acc);
      acc = mfma16x16x32(ahi[ks], bl, acc);
    }
    const float bov = b_o[ct*16 + c16];
#pragma unroll
    for (int r = 0; r < 4; ++r){
      const int R = 16*wave + 4*g + r;
      const long tok = winbase + (long)(R >> 3)*256 + (R & 7);
      out[tok*128 + ct*16 + c16] = acc[r] + bov;
    }
  }
}

extern "C" void kernel_launch(void* const* d_in, const int* in_sizes, int n_in,
                              void* d_out, int out_size, void* d_ws, size_t ws_size,
                              hipStream_t stream)
{
  const float* qq   = (const float*)d_in[0];
  const float* kk   = (const float*)d_in[1];
  const float* vv   = (const float*)d_in[2];
  const float* w_q  = (const float*)d_in[3];
  const float* b_q  = (const float*)d_in[4];
  const float* w_k  = (const float*)d_in[5];
  const float* b_k  = (const float*)d_in[6];
  const float* w_v  = (const float*)d_in[7];
  const float* b_v  = (const float*)d_in[8];
  const float* w_o  = (const float*)d_in[9];
  const float* b_o  = (const float*)d_in[10];
  const float* btab = (const float*)d_in[11];
  unsigned short* wsu = (unsigned short*)d_ws;
  float* out = (float*)d_out;

  prep_kernel<<<448, 256, 0, stream>>>(w_q, w_k, w_v, w_o, btab, wsu);
  fused_win_attn<<<4096, 256, 0, stream>>>(qq, kk, vv, b_q, b_k, b_v, b_o, wsu, out);
}